// Round 15
// baseline (61.324 us; speedup 1.0000x reference)
//
#include <hip/hip_runtime.h>
#include <hip/hip_bf16.h>

#define N_ROWS 8192
#define DIM 128

typedef short v8s  __attribute__((ext_vector_type(8)));   // 8 bf16 (4 VGPRs) MFMA A/B frag
typedef float v16f __attribute__((ext_vector_type(16)));  // 32x32 MFMA C/D frag
typedef float v2f  __attribute__((ext_vector_type(2)));   // packed-f32 pair (v_pk_*)
typedef unsigned int u32;

constexpr int NS = 16;                // j-splits (blockIdx.y)
constexpr int CW = N_ROWS / NS;       // 512 j-rows per split
constexpr int TILE_J = 32;            // LDS-staged j-rows per tile
constexpr int NT = CW / TILE_J;       // 16 tiles per block
constexpr int TB = TILE_J * DIM * 2;  // 8 KB per buffer
constexpr int BI = 256;               // block i-width (8 waves x 32 cols)
constexpr int NBX = N_ROWS / BI;      // 32 bx columns
constexpr float T2 = 0.0625f;         // THRESH^2: |pi-pj|<0.25 <=> d^2<0.0625
constexpr float C1 = 14.426950408889634f;  // 10*log2(e): exp(10*dot-10)=2^(C1*dot-C1)

// global->LDS async copy; size must be a literal (macro keeps it one).
#define GLDS(gptr, lptr, sz)                                                   \
  __builtin_amdgcn_global_load_lds(                                            \
      (const __attribute__((address_space(1))) u32*)(gptr),                    \
      (__attribute__((address_space(3))) u32*)(lptr), sz, 0, 0)

__device__ __forceinline__ unsigned short f2bf(float f) {
  __hip_bfloat16 h = __float2bfloat16(f);
  return __builtin_bit_cast(unsigned short, h);
}

// ---------------- kernel 1: L2-normalize rows + zero ticket counters ----------------
__global__ __launch_bounds__(256) void knorm(const float* __restrict__ emb,
                                             unsigned short* __restrict__ ebf,
                                             int* __restrict__ cnt) {
  if (blockIdx.x == 0 && threadIdx.x < NBX + 1) cnt[threadIdx.x] = 0;  // cnt_bx[32] + cnt2
  const int row  = blockIdx.x * 4 + (threadIdx.x >> 6);  // one wave per row
  const int lane = threadIdx.x & 63;
  const float2 v = *reinterpret_cast<const float2*>(emb + (size_t)row * DIM + lane * 2);
  float ss = fmaf(v.x, v.x, v.y * v.y);
#pragma unroll
  for (int off = 32; off > 0; off >>= 1) ss += __shfl_xor(ss, off);
  const float rn = 1.0f / sqrtf(ss);
  const unsigned int packed =
      (unsigned int)f2bf(v.x * rn) | ((unsigned int)f2bf(v.y * rn) << 16);
  *reinterpret_cast<unsigned int*>(ebf + (size_t)row * DIM + lane * 2) = packed;
}

// ---------------- kernel 2: R9 kmain VERBATIM + fused reduce tail ----------------
// Main loop is the measured-best R9 config (kmain=30.3us, absmax 0, zero bank
// conflicts). Tail (R10-validated ticket pattern): per-bx counter; the 16th
// finisher of column bx reduces rows [bx*256,+256); per-bx partials are then
// combined IN FIXED ORDER by the 32nd bx-finisher -> bit-deterministic scalar.
// Removes the kreduce and kfin launches (4 dispatches -> 2).
__global__ __launch_bounds__(512) void kmain(const unsigned short* __restrict__ ebf,
                                             const float* __restrict__ props,
                                             float* __restrict__ part,
                                             volatile float* __restrict__ bsx,
                                             volatile float* __restrict__ bcx,
                                             int* __restrict__ cnt,
                                             float* __restrict__ out) {
  const int tid  = threadIdx.x;
  const int lane = tid & 63;
  const int w    = tid >> 6;           // 0..7
  const int r31  = lane & 31;          // A-row / C-col index
  const int hi   = lane >> 5;          // 0..1
  const int i0   = blockIdx.x * BI;    // block i-range (256 cols)
  const int iw0  = i0 + w * 32;        // wave i-range
  const int jbase = blockIdx.y * CW;

  __shared__ __align__(1024) char sA[2 * TB + CW * 4];
  char* sprops = sA + 2 * TB;

  const int icol = iw0 + r31;          // this lane's output column

  // persistent B-frags: frag kk holds e[icol][kk*16 + hi*8 .. +8)
  v8s bfr[8];
#pragma unroll
  for (int kk = 0; kk < 8; ++kk)
    bfr[kk] = *reinterpret_cast<const v8s*>(ebf + (size_t)icol * DIM + kk * 16 + hi * 8);
  const float pc = props[icol];

  // stage props[jbase .. +512) into LDS: one 4B GLDS per thread
  GLDS(props + jbase + tid, sprops + w * 256, 4);

  // stage one 32-row A-tile: ONE 16B GLDS per thread; LDS linear,
  // source pre-swizzled (LDS chunk s of row r holds global chunk s ^ (r&7))
  auto stageA = [&](char* base, int tile) {
    const int jrow0 = jbase + tile * TILE_J;
    const int row   = w * 4 + (lane >> 4);             // 32 rows over 8 waves
    const int colb  = ((lane & 15) << 4) ^ ((row & 7) << 4);
    GLDS(ebf + (size_t)(jrow0 + row) * DIM + (colb >> 1), base + w * 1024, 16);
  };

  const int phase = (blockIdx.x * 5) & (NT - 1);       // convoy breaker
  stageA(sA, phase);
  __syncthreads();                     // tile(phase) + props ready

  v2f es2 = {0.f, 0.f}, ms2 = {0.f, 0.f}, ct2 = {0.f, 0.f};
  const int rswz = (r31 & 7) << 4;     // read-side XOR swizzle
  const v2f c1v = {C1, C1}, mc1v = {-C1, -C1}, pc2 = {pc, pc};

  for (int t = 0; t < NT; ++t) {
    const int tt = (t + phase) & (NT - 1);
    if (t + 1 < NT) stageA(sA + ((t + 1) & 1) * TB, (tt + 1) & (NT - 1));

    char* base = sA + (t & 1) * TB;
    const int jrow0 = jbase + tt * TILE_J;

    // A-frags: frag kk = e[jrow0 + r31][kk*16 + hi*8 .. +8) via swizzled slot
    v8s af[8];
#pragma unroll
    for (int kk = 0; kk < 8; ++kk)
      af[kk] = *reinterpret_cast<const v8s*>(
          base + r31 * 256 + ((kk * 32 + hi * 16) ^ rswz));

    v16f acc = {0.f, 0.f, 0.f, 0.f, 0.f, 0.f, 0.f, 0.f,
                0.f, 0.f, 0.f, 0.f, 0.f, 0.f, 0.f, 0.f};
#pragma unroll
    for (int kk = 0; kk < 8; ++kk)
      acc = __builtin_amdgcn_mfma_f32_32x32x16_bf16(af[kk], bfr[kk], acc, 0, 0, 0);

    if ((unsigned)(jrow0 - i0) < (unsigned)BI) {   // tile may contain the diagonal
#pragma unroll
      for (int r = 0; r < 8; ++r) {
        const int row0 = ((2 * r) & 3) + 8 * (r >> 1) + 4 * hi;  // rows row0, row0+1
        const v2f pj2  = *reinterpret_cast<const v2f*>(
            sprops + ((size_t)tt * 32 + row0) * 4);              // broadcast read
        const v2f dot2 = {acc[2 * r], acc[2 * r + 1]};
        const v2f arg  = __builtin_elementwise_fma(dot2, c1v, mc1v);
        const float ex0 = __builtin_amdgcn_exp2f(arg.x);
        const float ex1 = __builtin_amdgcn_exp2f(arg.y);
        const int jr0 = jrow0 + row0;
        const bool neq0 = (jr0 != icol), neq1 = (jr0 + 1 != icol);
        const v2f exv = {neq0 ? ex0 : 0.f, neq1 ? ex1 : 0.f};
        es2 += exv;
        const v2f d = pc2 - pj2, dsq = d * d;
        const v2f msk = {(neq0 && dsq.x < T2) ? 1.f : 0.f,
                         (neq1 && dsq.y < T2) ? 1.f : 0.f};
        ct2 += msk;
        ms2 = __builtin_elementwise_fma(msk, dot2, ms2);
      }
    } else {
#pragma unroll
      for (int r = 0; r < 8; ++r) {
        const int row0 = ((2 * r) & 3) + 8 * (r >> 1) + 4 * hi;
        const v2f pj2  = *reinterpret_cast<const v2f*>(
            sprops + ((size_t)tt * 32 + row0) * 4);
        const v2f dot2 = {acc[2 * r], acc[2 * r + 1]};
        const v2f arg  = __builtin_elementwise_fma(dot2, c1v, mc1v);
        const v2f exv  = {__builtin_amdgcn_exp2f(arg.x), __builtin_amdgcn_exp2f(arg.y)};
        es2 += exv;
        const v2f d = pc2 - pj2, dsq = d * d;
        const v2f msk = {(dsq.x < T2) ? 1.f : 0.f, (dsq.y < T2) ? 1.f : 0.f};
        ct2 += msk;
        ms2 = __builtin_elementwise_fma(msk, dot2, ms2);
      }
    }
    __syncthreads();   // all reads of cur done; next tile staged
  }

  // combine pair-halves, then sum the two hi-halves
  float es = es2.x + es2.y, ms = ms2.x + ms2.y, ct = ct2.x + ct2.y;
  es += __shfl_xor(es, 32);
  ms += __shfl_xor(ms, 32);
  ct += __shfl_xor(ct, 32);

  if (hi == 0) {
    float* p0 = part + (size_t)blockIdx.y * 3 * N_ROWS;  // slot = j-split; i disjoint per bx
    p0[icol]              = es;
    p0[N_ROWS + icol]     = ms;
    p0[2 * N_ROWS + icol] = ct;
  }

  // ---------- fused reduce tail (ticket per bx, then global ticket) ----------
  __shared__ int sticket;
  __syncthreads();                         // all partial stores issued
  if (tid == 0) {
    __threadfence();                       // publish partials (device scope)
    sticket = atomicAdd(&cnt[blockIdx.x], 1);
  }
  __syncthreads();
  if (sticket == NS - 1) {                 // last j-split finisher of column bx
    __threadfence();                       // acquire: see all 16 splits' partials
    float val = 0.f, vld = 0.f;
    if (tid < BI) {
      const int row = blockIdx.x * BI + tid;
      float esr = 0.f, msr = 0.f, ctr = 0.f;
#pragma unroll
      for (int sp = 0; sp < NS; ++sp) {
        const float* p0 = part + (size_t)sp * 3 * N_ROWS;
        esr += p0[row];
        msr += p0[N_ROWS + row];
        ctr += p0[2 * N_ROWS + row];
      }
      const float lse = 10.0f + logf(esr);               // logsumexp, M=10
      const float per = (ctr * lse - 10.0f * msr) / fmaxf(ctr, 1.0f);
      val = (ctr > 0.f) ? per : 0.f;
      vld = (ctr > 0.f) ? 1.f : 0.f;
    }
#pragma unroll
    for (int off = 32; off > 0; off >>= 1) {
      val += __shfl_xor(val, off);
      vld += __shfl_xor(vld, off);
    }
    __shared__ float sv[8], sc[8];
    if (lane == 0) { sv[w] = val; sc[w] = vld; }
    __syncthreads();
    if (tid == 0) {
      float s = sv[0] + sv[1] + sv[2] + sv[3];           // waves 4..7 had zeros
      float c = sc[0] + sc[1] + sc[2] + sc[3];
      bsx[blockIdx.x] = s;
      bcx[blockIdx.x] = c;
      __threadfence();
      const int t2 = atomicAdd(&cnt[NBX], 1);
      if (t2 == NBX - 1) {                 // final finisher: fixed-order sum
        __threadfence();
        float S = 0.f, C = 0.f;
        for (int k = 0; k < NBX; ++k) { S += bsx[k]; C += bcx[k]; }
        out[0] = (C > 0.f) ? (S / C) : 0.f;
      }
    }
  }
}

extern "C" void kernel_launch(void* const* d_in, const int* in_sizes, int n_in,
                              void* d_out, int out_size, void* d_ws, size_t ws_size,
                              hipStream_t stream) {
  const float* emb   = (const float*)d_in[0];
  const float* props = (const float*)d_in[1];
  float* out = (float*)d_out;

  // ws layout: [0,2MB) bf16 normalized embeddings; NS*3*N f32 partials;
  // bsx[32]; bcx[32]; cnt[33] (cnt_bx[32] + cnt2)
  unsigned short* ebf = (unsigned short*)d_ws;
  const size_t EBF_BYTES  = (size_t)N_ROWS * DIM * 2;
  const size_t PART_BYTES = (size_t)NS * 3 * N_ROWS * 4;
  float* part = (float*)((char*)d_ws + EBF_BYTES);
  float* bsx  = (float*)((char*)d_ws + EBF_BYTES + PART_BYTES);
  float* bcx  = bsx + NBX;
  int*   cnt  = (int*)(bcx + NBX);

  knorm<<<N_ROWS / 4, 256, 0, stream>>>(emb, ebf, cnt);
  kmain<<<dim3(N_ROWS / BI, NS), 512, 0, stream>>>(ebf, props, part, bsx, bcx, cnt, out);
}

// Round 16
// 51.802 us; speedup vs baseline: 1.1838x; 1.1838x over previous
//
#include <hip/hip_runtime.h>
#include <hip/hip_bf16.h>

#define N_ROWS 8192
#define DIM 128

typedef short v8s  __attribute__((ext_vector_type(8)));   // 8 bf16 (4 VGPRs) MFMA A/B frag
typedef float v16f __attribute__((ext_vector_type(16)));  // 32x32 MFMA C/D frag
typedef float v2f  __attribute__((ext_vector_type(2)));   // packed-f32 pair (v_pk_*)
typedef unsigned int u32;

constexpr int NS = 16;                // j-splits (blockIdx.y)
constexpr int CW = N_ROWS / NS;       // 512 j-rows per split
constexpr int NSLOT = NS;             // partial slots (one per j-split)
constexpr int TILE_J = 32;            // LDS-staged j-rows per tile
constexpr int NT = CW / TILE_J;       // 16 tiles per block
constexpr int TB = TILE_J * DIM * 2;  // 8 KB per buffer
constexpr int BI = 512;               // block i-width (8 waves x 64 cols)
constexpr float T2 = 0.0625f;         // THRESH^2: |pi-pj|<0.25 <=> d^2<0.0625
constexpr float C1 = 14.426950408889634f;  // 10*log2(e): exp(10*dot-10)=2^(C1*dot-C1)

// global->LDS async copy; size must be a literal (macro keeps it one).
#define GLDS(gptr, lptr, sz)                                                   \
  __builtin_amdgcn_global_load_lds(                                            \
      (const __attribute__((address_space(1))) u32*)(gptr),                    \
      (__attribute__((address_space(3))) u32*)(lptr), sz, 0, 0)

__device__ __forceinline__ unsigned short f2bf(float f) {
  __hip_bfloat16 h = __float2bfloat16(f);
  return __builtin_bit_cast(unsigned short, h);
}

// ---------------- kernel 1: L2-normalize rows, cast to bf16 ----------------
__global__ __launch_bounds__(256) void knorm(const float* __restrict__ emb,
                                             unsigned short* __restrict__ ebf) {
  const int row  = blockIdx.x * 4 + (threadIdx.x >> 6);  // one wave per row
  const int lane = threadIdx.x & 63;
  const float2 v = *reinterpret_cast<const float2*>(emb + (size_t)row * DIM + lane * 2);
  float ss = fmaf(v.x, v.x, v.y * v.y);
#pragma unroll
  for (int off = 32; off > 0; off >>= 1) ss += __shfl_xor(ss, off);
  const float rn = 1.0f / sqrtf(ss);
  const unsigned int packed =
      (unsigned int)f2bf(v.x * rn) | ((unsigned int)f2bf(v.y * rn) << 16);
  *reinterpret_cast<unsigned int*>(ebf + (size_t)row * DIM + lane * 2) = packed;
}

// ---------------- kernel 2: fused sim-GEMM + row stats, 64 i-cols/wave ----------------
// R9 skeleton (8-wave blocks, LDS double-buffer, one 16B GLDS/thread/tile,
// pre-swizzled source + XOR ds_read, packed-f32 epilogue, NO fences — R15
// showed device-scope fences in a heavyweight kernel cost +28us) with the
// R12 idea DE-CONFOUNDED: each wave owns 64 i-cols (two B-frag sets, two acc
// chains) sharing ONE af[8] read. Grid 16x16 = 256 blocks = 1 block/CU, so
// occupancy is grid-capped at 8 waves/CU for any VGPR <= 256 — the register
// cost of the second set is free (R12's 4-wave-block confound removed).
// LDS-read traffic/CU halves (2MB -> 1MB); MFMA:ds_read = 2:1.
// C/D layout (m74/m101): col = lane&31, row = (reg&3)+8*(reg>>2)+4*(lane>>5).
__global__ __launch_bounds__(512) void kmain(const unsigned short* __restrict__ ebf,
                                             const float* __restrict__ props,
                                             float* __restrict__ part) {
  const int tid  = threadIdx.x;
  const int lane = tid & 63;
  const int w    = tid >> 6;           // 0..7
  const int r31  = lane & 31;          // A-row / C-col index
  const int hi   = lane >> 5;          // 0..1
  const int i0   = blockIdx.x * BI;    // block i-range (512 cols)
  const int iw0  = i0 + w * 64;        // wave i-range (64 cols, 2 sets)
  const int jbase = blockIdx.y * CW;

  __shared__ __align__(1024) char sA[2 * TB + CW * 4];
  char* sprops = sA + 2 * TB;

  const int icol0 = iw0 + r31;         // set-0 output column
  const int icol1 = iw0 + 32 + r31;    // set-1 output column

  // persistent B-frags: frag kk holds e[icol][kk*16 + hi*8 .. +8)
  v8s bfr0[8], bfr1[8];
#pragma unroll
  for (int kk = 0; kk < 8; ++kk) {
    bfr0[kk] = *reinterpret_cast<const v8s*>(ebf + (size_t)icol0 * DIM + kk * 16 + hi * 8);
    bfr1[kk] = *reinterpret_cast<const v8s*>(ebf + (size_t)icol1 * DIM + kk * 16 + hi * 8);
  }
  const float pc0 = props[icol0];
  const float pc1 = props[icol1];

  // stage props[jbase .. +512) into LDS: one 4B GLDS per thread
  GLDS(props + jbase + tid, sprops + w * 256, 4);

  // stage one 32-row A-tile: ONE 16B GLDS per thread; LDS linear,
  // source pre-swizzled (LDS chunk s of row r holds global chunk s ^ (r&7))
  auto stageA = [&](char* base, int tile) {
    const int jrow0 = jbase + tile * TILE_J;
    const int row   = w * 4 + (lane >> 4);             // 32 rows over 8 waves
    const int colb  = ((lane & 15) << 4) ^ ((row & 7) << 4);
    GLDS(ebf + (size_t)(jrow0 + row) * DIM + (colb >> 1), base + w * 1024, 16);
  };

  const int phase = (blockIdx.x * 5) & (NT - 1);       // convoy breaker
  stageA(sA, phase);
  __syncthreads();                     // tile(phase) + props ready

  v2f es0 = {0.f, 0.f}, ms0 = {0.f, 0.f}, ct0 = {0.f, 0.f};
  v2f es1 = {0.f, 0.f}, ms1 = {0.f, 0.f}, ct1 = {0.f, 0.f};
  const int rswz = (r31 & 7) << 4;     // read-side XOR swizzle
  const v2f c1v = {C1, C1}, mc1v = {-C1, -C1};
  const v2f pc02 = {pc0, pc0}, pc12 = {pc1, pc1};

  for (int t = 0; t < NT; ++t) {
    const int tt = (t + phase) & (NT - 1);
    if (t + 1 < NT) stageA(sA + ((t + 1) & 1) * TB, (tt + 1) & (NT - 1));

    char* base = sA + (t & 1) * TB;
    const int jrow0 = jbase + tt * TILE_J;

    // ONE af[8] read feeds BOTH MFMA chains
    v8s af[8];
#pragma unroll
    for (int kk = 0; kk < 8; ++kk)
      af[kk] = *reinterpret_cast<const v8s*>(
          base + r31 * 256 + ((kk * 32 + hi * 16) ^ rswz));

    v16f acc0 = {0.f, 0.f, 0.f, 0.f, 0.f, 0.f, 0.f, 0.f,
                 0.f, 0.f, 0.f, 0.f, 0.f, 0.f, 0.f, 0.f};
    v16f acc1 = acc0;
#pragma unroll
    for (int kk = 0; kk < 8; ++kk) {
      acc0 = __builtin_amdgcn_mfma_f32_32x32x16_bf16(af[kk], bfr0[kk], acc0, 0, 0, 0);
      acc1 = __builtin_amdgcn_mfma_f32_32x32x16_bf16(af[kk], bfr1[kk], acc1, 0, 0, 0);
    }

    if ((unsigned)(jrow0 - i0) < (unsigned)BI) {   // tile may contain the diagonal
#pragma unroll
      for (int r = 0; r < 8; ++r) {
        const int row0 = ((2 * r) & 3) + 8 * (r >> 1) + 4 * hi;  // rows row0, row0+1
        const v2f pj2  = *reinterpret_cast<const v2f*>(
            sprops + ((size_t)tt * 32 + row0) * 4);              // broadcast read
        const int jr0 = jrow0 + row0;
        {
          const v2f dot2 = {acc0[2 * r], acc0[2 * r + 1]};
          const v2f arg  = __builtin_elementwise_fma(dot2, c1v, mc1v);
          const bool neq0 = (jr0 != icol0), neq1 = (jr0 + 1 != icol0);
          const v2f exv = {neq0 ? __builtin_amdgcn_exp2f(arg.x) : 0.f,
                           neq1 ? __builtin_amdgcn_exp2f(arg.y) : 0.f};
          es0 += exv;
          const v2f d = pc02 - pj2, dsq = d * d;
          const v2f msk = {(neq0 && dsq.x < T2) ? 1.f : 0.f,
                           (neq1 && dsq.y < T2) ? 1.f : 0.f};
          ct0 += msk;
          ms0 = __builtin_elementwise_fma(msk, dot2, ms0);
        }
        {
          const v2f dot2 = {acc1[2 * r], acc1[2 * r + 1]};
          const v2f arg  = __builtin_elementwise_fma(dot2, c1v, mc1v);
          const bool neq0 = (jr0 != icol1), neq1 = (jr0 + 1 != icol1);
          const v2f exv = {neq0 ? __builtin_amdgcn_exp2f(arg.x) : 0.f,
                           neq1 ? __builtin_amdgcn_exp2f(arg.y) : 0.f};
          es1 += exv;
          const v2f d = pc12 - pj2, dsq = d * d;
          const v2f msk = {(neq0 && dsq.x < T2) ? 1.f : 0.f,
                           (neq1 && dsq.y < T2) ? 1.f : 0.f};
          ct1 += msk;
          ms1 = __builtin_elementwise_fma(msk, dot2, ms1);
        }
      }
    } else {
#pragma unroll
      for (int r = 0; r < 8; ++r) {
        const int row0 = ((2 * r) & 3) + 8 * (r >> 1) + 4 * hi;
        const v2f pj2  = *reinterpret_cast<const v2f*>(
            sprops + ((size_t)tt * 32 + row0) * 4);
        {
          const v2f dot2 = {acc0[2 * r], acc0[2 * r + 1]};
          const v2f arg  = __builtin_elementwise_fma(dot2, c1v, mc1v);
          const v2f exv  = {__builtin_amdgcn_exp2f(arg.x), __builtin_amdgcn_exp2f(arg.y)};
          es0 += exv;
          const v2f d = pc02 - pj2, dsq = d * d;
          const v2f msk = {(dsq.x < T2) ? 1.f : 0.f, (dsq.y < T2) ? 1.f : 0.f};
          ct0 += msk;
          ms0 = __builtin_elementwise_fma(msk, dot2, ms0);
        }
        {
          const v2f dot2 = {acc1[2 * r], acc1[2 * r + 1]};
          const v2f arg  = __builtin_elementwise_fma(dot2, c1v, mc1v);
          const v2f exv  = {__builtin_amdgcn_exp2f(arg.x), __builtin_amdgcn_exp2f(arg.y)};
          es1 += exv;
          const v2f d = pc12 - pj2, dsq = d * d;
          const v2f msk = {(dsq.x < T2) ? 1.f : 0.f, (dsq.y < T2) ? 1.f : 0.f};
          ct1 += msk;
          ms1 = __builtin_elementwise_fma(msk, dot2, ms1);
        }
      }
    }
    __syncthreads();   // all reads of cur done; next tile staged
  }

  // combine pair-halves, then sum the two hi-halves (lanes l and l+32 hold
  // complementary j-row subsets for the same icol)
  float esa = es0.x + es0.y, msa = ms0.x + ms0.y, cta = ct0.x + ct0.y;
  float esb = es1.x + es1.y, msb = ms1.x + ms1.y, ctb = ct1.x + ct1.y;
  esa += __shfl_xor(esa, 32);  msa += __shfl_xor(msa, 32);  cta += __shfl_xor(cta, 32);
  esb += __shfl_xor(esb, 32);  msb += __shfl_xor(msb, 32);  ctb += __shfl_xor(ctb, 32);

  if (hi == 0) {
    float* p0 = part + (size_t)blockIdx.y * 3 * N_ROWS;  // slot = j-split; i disjoint per bx
    p0[icol0]              = esa;
    p0[N_ROWS + icol0]     = msa;
    p0[2 * N_ROWS + icol0] = cta;
    p0[icol1]              = esb;
    p0[N_ROWS + icol1]     = msb;
    p0[2 * N_ROWS + icol1] = ctb;
  }
}

// ---------------- kernel 3: per-row finalize + per-block partial sums ----------------
__global__ __launch_bounds__(64) void kreduce(const float* __restrict__ part,
                                              float* __restrict__ bs,
                                              float* __restrict__ bc) {
  const int row = blockIdx.x * 64 + threadIdx.x;
  float es = 0.f, ms = 0.f, ct = 0.f;
#pragma unroll
  for (int sp = 0; sp < NSLOT; ++sp) {
    const float* p0 = part + (size_t)sp * 3 * N_ROWS;
    es += p0[row];
    ms += p0[N_ROWS + row];
    ct += p0[2 * N_ROWS + row];
  }
  const float lse = 10.0f + logf(es);                       // logsumexp, M=10
  const float per = (ct * lse - 10.0f * ms) / fmaxf(ct, 1.0f);
  float val = (ct > 0.f) ? per : 0.f;
  float vld = (ct > 0.f) ? 1.f : 0.f;
#pragma unroll
  for (int off = 32; off > 0; off >>= 1) {
    val += __shfl_xor(val, off);
    vld += __shfl_xor(vld, off);
  }
  if (threadIdx.x == 0) {
    bs[blockIdx.x] = val;
    bc[blockIdx.x] = vld;
  }
}

// ---------------- kernel 4: final scalar ----------------
__global__ __launch_bounds__(64) void kfin(const float* __restrict__ bs,
                                           const float* __restrict__ bc,
                                           float* __restrict__ out) {
  const int l = threadIdx.x;
  float s = bs[l] + bs[l + 64];
  float c = bc[l] + bc[l + 64];
#pragma unroll
  for (int off = 32; off > 0; off >>= 1) {
    s += __shfl_xor(s, off);
    c += __shfl_xor(c, off);
  }
  if (l == 0) out[0] = (c > 0.f) ? (s / c) : 0.f;
}

extern "C" void kernel_launch(void* const* d_in, const int* in_sizes, int n_in,
                              void* d_out, int out_size, void* d_ws, size_t ws_size,
                              hipStream_t stream) {
  const float* emb   = (const float*)d_in[0];
  const float* props = (const float*)d_in[1];
  float* out = (float*)d_out;

  // ws layout: [0, 2MB) bf16 normalized embeddings; then NSLOT*3*N f32 partials;
  // then 128+128 f32 block partials
  unsigned short* ebf = (unsigned short*)d_ws;
  const size_t EBF_BYTES  = (size_t)N_ROWS * DIM * 2;
  const size_t PART_BYTES = (size_t)NSLOT * 3 * N_ROWS * 4;
  float* part = (float*)((char*)d_ws + EBF_BYTES);
  float* bs   = (float*)((char*)d_ws + EBF_BYTES + PART_BYTES);
  float* bc   = bs + 128;

  knorm<<<N_ROWS / 4, 256, 0, stream>>>(emb, ebf);
  kmain<<<dim3(N_ROWS / BI, NS), 512, 0, stream>>>(ebf, props, part);
  kreduce<<<N_ROWS / 64, 64, 0, stream>>>(part, bs, bc);
  kfin<<<1, 64, 0, stream>>>(bs, bc, out);
}